// Round 1
// 273.403 us; speedup vs baseline: 1.0015x; 1.0015x over previous
//
#include <hip/hip_runtime.h>

#define TPB 256
#define U 4                  // independent float4 loads per array per thread per iter
#define CHUNK (TPB * U)      // float4s per chunk (1024)
#define NBLK 2048            // 8 blocks/CU; partials = 16 KB of d_ws

__device__ __forceinline__ float relf(float x, float y) {
    float d = fabsf(x - y);
    float r = d * __builtin_amdgcn_rcpf(y);   // ~1 ulp; matches reference within tol
    return (y == 0.0f) ? d : r;               // branchless cndmask
}

__global__ __launch_bounds__(TPB) void rdl_partial_kernel(
    const float4* __restrict__ x, const float4* __restrict__ y,
    double* __restrict__ partial, int nvec) {

    const int t = threadIdx.x;
    double accd = 0.0;

    // Barrier-free grid-stride main loop: 8 independent dwordx4 loads in
    // flight per thread, no LDS, no vmcnt(0) drain. Latency hidden by
    // TLP (8 waves/SIMD, no LDS cap) + ILP.
    const int nchunk = nvec / CHUNK;
    for (int c = blockIdx.x; c < nchunk; c += gridDim.x) {
        const int base = c * CHUNK + t;
        float4 xv[U], yv[U];
        #pragma unroll
        for (int u = 0; u < U; ++u) xv[u] = x[base + u * TPB];
        #pragma unroll
        for (int u = 0; u < U; ++u) yv[u] = y[base + u * TPB];

        float a0 = 0.f, a1 = 0.f;   // short f32 chains (32 terms), promoted below
        #pragma unroll
        for (int u = 0; u < U; ++u) {
            a0 += relf(xv[u].x, yv[u].x) + relf(xv[u].z, yv[u].z);
            a1 += relf(xv[u].y, yv[u].y) + relf(xv[u].w, yv[u].w);
        }
        accd += (double)(a0 + a1);
    }

    // tail (empty for N=2^25: CHUNK divides nvec), kept for generality
    for (int i = nchunk * CHUNK + blockIdx.x * TPB + t; i < nvec;
         i += gridDim.x * TPB) {
        float4 xv = x[i], yv = y[i];
        accd += (double)(relf(xv.x, yv.x) + relf(xv.z, yv.z)
                       + relf(xv.y, yv.y) + relf(xv.w, yv.w));
    }

    // wave (64-lane) f64 reduction
    double acc = accd;
    for (int off = 32; off > 0; off >>= 1)
        acc += __shfl_down(acc, off, 64);
    __shared__ double smem[TPB / 64];
    const int lane = t & 63, w = t >> 6;
    if (lane == 0) smem[w] = acc;
    __syncthreads();
    if (t == 0) {
        double s = 0.0;
        #pragma unroll
        for (int wi = 0; wi < TPB / 64; ++wi) s += smem[wi];
        partial[blockIdx.x] = s;
    }
}

__global__ __launch_bounds__(TPB) void rdl_final_kernel(
    const double* __restrict__ partial, float* __restrict__ out,
    int nblocks, double invN) {
    double acc = 0.0;
    for (int i = threadIdx.x; i < nblocks; i += TPB)
        acc += partial[i];
    for (int off = 32; off > 0; off >>= 1)
        acc += __shfl_down(acc, off, 64);
    __shared__ double smem[TPB / 64];
    const int lane = threadIdx.x & 63, wid = threadIdx.x >> 6;
    if (lane == 0) smem[wid] = acc;
    __syncthreads();
    if (threadIdx.x == 0) {
        double s = 0.0;
        #pragma unroll
        for (int w = 0; w < TPB / 64; ++w) s += smem[w];
        out[0] = (float)(s * invN);
    }
}

extern "C" void kernel_launch(void* const* d_in, const int* in_sizes, int n_in,
                              void* d_out, int out_size, void* d_ws, size_t ws_size,
                              hipStream_t stream) {
    const float* x = (const float*)d_in[0];
    const float* y = (const float*)d_in[1];
    int n = in_sizes[0];          // 33554432, divisible by 4
    int nvec = n / 4;

    double* partial = (double*)d_ws;   // NBLK * 8 = 16 KB scratch

    rdl_partial_kernel<<<NBLK, TPB, 0, stream>>>(
        (const float4*)x, (const float4*)y, partial, nvec);
    rdl_final_kernel<<<1, TPB, 0, stream>>>(
        partial, (float*)d_out, NBLK, 1.0 / (double)n);
}

// Round 2
// 261.151 us; speedup vs baseline: 1.0485x; 1.0469x over previous
//
#include <hip/hip_runtime.h>

#define TPB 256
#define U 4                  // independent 16B loads per array per thread per iter
#define CHUNK (TPB * U)      // float4s per chunk (1024)
#define NBLK 2048            // 8 blocks/CU; partials = 16 KB of d_ws

typedef float vf4 __attribute__((ext_vector_type(4)));

__device__ __forceinline__ float relf(float x, float y) {
    float d = fabsf(x - y);
    float r = d * __builtin_amdgcn_rcpf(y);   // ~1 ulp; matches reference within tol
    return (y == 0.0f) ? d : r;               // branchless cndmask
}

__global__ __launch_bounds__(TPB) void rdl_partial_kernel(
    const vf4* __restrict__ x, const vf4* __restrict__ y,
    double* __restrict__ partial, int nvec) {

    const int t = threadIdx.x;
    double accd = 0.0;

    // Stream-untangling: x on the cached path (134 MB < 256 MB L3 -> ~100%
    // L3-resident once warm), y via non-temporal loads (no L3/L2 allocation,
    // pure HBM stream). Stops the two 134 MB streams from thrashing the
    // 256 MB Infinity Cache to 50% hit and from lockstep channel aliasing.
    const int nchunk = nvec / CHUNK;
    for (int c = blockIdx.x; c < nchunk; c += gridDim.x) {
        const int base = c * CHUNK + t;
        vf4 xv[U], yv[U];
        #pragma unroll
        for (int u = 0; u < U; ++u)
            yv[u] = __builtin_nontemporal_load(y + base + u * TPB);
        #pragma unroll
        for (int u = 0; u < U; ++u)
            xv[u] = x[base + u * TPB];

        float a0 = 0.f, a1 = 0.f;   // short f32 chains (32 terms), promoted below
        #pragma unroll
        for (int u = 0; u < U; ++u) {
            a0 += relf(xv[u][0], yv[u][0]) + relf(xv[u][2], yv[u][2]);
            a1 += relf(xv[u][1], yv[u][1]) + relf(xv[u][3], yv[u][3]);
        }
        accd += (double)(a0 + a1);
    }

    // tail (empty for N=2^25: CHUNK divides nvec), kept for generality
    for (int i = nchunk * CHUNK + blockIdx.x * TPB + t; i < nvec;
         i += gridDim.x * TPB) {
        vf4 xv = x[i], yv = y[i];
        accd += (double)(relf(xv[0], yv[0]) + relf(xv[2], yv[2])
                       + relf(xv[1], yv[1]) + relf(xv[3], yv[3]));
    }

    // wave (64-lane) f64 reduction
    double acc = accd;
    for (int off = 32; off > 0; off >>= 1)
        acc += __shfl_down(acc, off, 64);
    __shared__ double smem[TPB / 64];
    const int lane = t & 63, w = t >> 6;
    if (lane == 0) smem[w] = acc;
    __syncthreads();
    if (t == 0) {
        double s = 0.0;
        #pragma unroll
        for (int wi = 0; wi < TPB / 64; ++wi) s += smem[wi];
        partial[blockIdx.x] = s;
    }
}

__global__ __launch_bounds__(TPB) void rdl_final_kernel(
    const double* __restrict__ partial, float* __restrict__ out,
    int nblocks, double invN) {
    double acc = 0.0;
    for (int i = threadIdx.x; i < nblocks; i += TPB)
        acc += partial[i];
    for (int off = 32; off > 0; off >>= 1)
        acc += __shfl_down(acc, off, 64);
    __shared__ double smem[TPB / 64];
    const int lane = threadIdx.x & 63, wid = threadIdx.x >> 6;
    if (lane == 0) smem[wid] = acc;
    __syncthreads();
    if (threadIdx.x == 0) {
        double s = 0.0;
        #pragma unroll
        for (int w = 0; w < TPB / 64; ++w) s += smem[w];
        out[0] = (float)(s * invN);
    }
}

extern "C" void kernel_launch(void* const* d_in, const int* in_sizes, int n_in,
                              void* d_out, int out_size, void* d_ws, size_t ws_size,
                              hipStream_t stream) {
    const float* x = (const float*)d_in[0];
    const float* y = (const float*)d_in[1];
    int n = in_sizes[0];          // 33554432, divisible by 4
    int nvec = n / 4;

    double* partial = (double*)d_ws;   // NBLK * 8 = 16 KB scratch

    rdl_partial_kernel<<<NBLK, TPB, 0, stream>>>(
        (const vf4*)x, (const vf4*)y, partial, nvec);
    rdl_final_kernel<<<1, TPB, 0, stream>>>(
        partial, (float*)d_out, NBLK, 1.0 / (double)n);
}

// Round 3
// 247.988 us; speedup vs baseline: 1.1042x; 1.0531x over previous
//
#include <hip/hip_runtime.h>

#define TPB 256
#define U 4                  // independent 16B loads per array per thread per iter
#define CHUNK (TPB * U)      // float4s per chunk (1024)
#define NBLK 2048            // 8 blocks/CU; partials = 16 KB of d_ws

typedef float vf4 __attribute__((ext_vector_type(4)));

__device__ __forceinline__ float relf(float x, float y) {
    float d = fabsf(x - y);
    float r = d * __builtin_amdgcn_rcpf(y);   // ~1 ulp; matches reference within tol
    return (y == 0.0f) ? d : r;               // branchless cndmask
}

__global__ __launch_bounds__(TPB) void rdl_partial_kernel(
    const vf4* __restrict__ x, const vf4* __restrict__ y,
    double* __restrict__ partial, int nvec) {

    const int t = threadIdx.x;
    double accd = 0.0;

    // Both streams non-temporal: single-use data, no L2/L3 allocation.
    // Decouples kernel from the harness re-poison's L3 churn entirely;
    // pure HBM streaming read of 268 MB. (Round-2 A/B: NT on y alone took
    // the partial kernel 99 -> ~75 us; x's cached path was still ~50%-miss
    // and allocate-coupled.)
    const int nchunk = nvec / CHUNK;
    for (int c = blockIdx.x; c < nchunk; c += gridDim.x) {
        const int base = c * CHUNK + t;
        vf4 xv[U], yv[U];
        #pragma unroll
        for (int u = 0; u < U; ++u)
            yv[u] = __builtin_nontemporal_load(y + base + u * TPB);
        #pragma unroll
        for (int u = 0; u < U; ++u)
            xv[u] = __builtin_nontemporal_load(x + base + u * TPB);

        float a0 = 0.f, a1 = 0.f;   // short f32 chains (32 terms), promoted below
        #pragma unroll
        for (int u = 0; u < U; ++u) {
            a0 += relf(xv[u][0], yv[u][0]) + relf(xv[u][2], yv[u][2]);
            a1 += relf(xv[u][1], yv[u][1]) + relf(xv[u][3], yv[u][3]);
        }
        accd += (double)(a0 + a1);
    }

    // tail (empty for N=2^25: CHUNK divides nvec), kept for generality
    for (int i = nchunk * CHUNK + blockIdx.x * TPB + t; i < nvec;
         i += gridDim.x * TPB) {
        vf4 xv = x[i], yv = y[i];
        accd += (double)(relf(xv[0], yv[0]) + relf(xv[2], yv[2])
                       + relf(xv[1], yv[1]) + relf(xv[3], yv[3]));
    }

    // wave (64-lane) f64 reduction
    double acc = accd;
    for (int off = 32; off > 0; off >>= 1)
        acc += __shfl_down(acc, off, 64);
    __shared__ double smem[TPB / 64];
    const int lane = t & 63, w = t >> 6;
    if (lane == 0) smem[w] = acc;
    __syncthreads();
    if (t == 0) {
        double s = 0.0;
        #pragma unroll
        for (int wi = 0; wi < TPB / 64; ++wi) s += smem[wi];
        partial[blockIdx.x] = s;
    }
}

__global__ __launch_bounds__(TPB) void rdl_final_kernel(
    const double* __restrict__ partial, float* __restrict__ out,
    int nblocks, double invN) {
    double acc = 0.0;
    for (int i = threadIdx.x; i < nblocks; i += TPB)
        acc += partial[i];
    for (int off = 32; off > 0; off >>= 1)
        acc += __shfl_down(acc, off, 64);
    __shared__ double smem[TPB / 64];
    const int lane = threadIdx.x & 63, wid = threadIdx.x >> 6;
    if (lane == 0) smem[wid] = acc;
    __syncthreads();
    if (threadIdx.x == 0) {
        double s = 0.0;
        #pragma unroll
        for (int w = 0; w < TPB / 64; ++w) s += smem[w];
        out[0] = (float)(s * invN);
    }
}

extern "C" void kernel_launch(void* const* d_in, const int* in_sizes, int n_in,
                              void* d_out, int out_size, void* d_ws, size_t ws_size,
                              hipStream_t stream) {
    const float* x = (const float*)d_in[0];
    const float* y = (const float*)d_in[1];
    int n = in_sizes[0];          // 33554432, divisible by 4
    int nvec = n / 4;

    double* partial = (double*)d_ws;   // NBLK * 8 = 16 KB scratch

    rdl_partial_kernel<<<NBLK, TPB, 0, stream>>>(
        (const vf4*)x, (const vf4*)y, partial, nvec);
    rdl_final_kernel<<<1, TPB, 0, stream>>>(
        partial, (float*)d_out, NBLK, 1.0 / (double)n);
}